// Round 4
// baseline (486.170 us; speedup 1.0000x reference)
//
#include <hip/hip_runtime.h>
#include <hip/hip_bf16.h>
#include <stdint.h>

// Problem dims (fixed): x [1,128,128,1024], E=1024, NH=16, D=64, M=16384.

typedef __attribute__((ext_vector_type(4))) float floatx4;
typedef __attribute__((ext_vector_type(8))) short shortx8;

static __device__ __forceinline__ float bf2f(unsigned short h) {
  return __uint_as_float(((unsigned int)h) << 16);
}
static __device__ __forceinline__ unsigned short f2bf(float f) {
  unsigned int u = __float_as_uint(f);
  u += 0x7fffu + ((u >> 16) & 1u);  // RNE
  return (unsigned short)(u >> 16);
}

static __device__ __forceinline__ void gload16(const void* g, void* l) {
  __builtin_amdgcn_global_load_lds(
      (const __attribute__((address_space(1))) void*)g,
      (__attribute__((address_space(3))) void*)l, 16, 0, 0);
}

// ---------------- merged f32 -> bf16 convert ----------------
__global__ __launch_bounds__(256) void cvt_all(
    const float* __restrict__ x, const float* __restrict__ Wq,
    const float* __restrict__ Wk, const float* __restrict__ Wv,
    const float* __restrict__ Wo, unsigned short* __restrict__ xb,
    unsigned short* __restrict__ wqkvb, unsigned short* __restrict__ wob) {
  const int b = blockIdx.x;
  const float* src;
  unsigned short* dst;
  int off;
  if (b < 16384) {
    src = x; dst = xb; off = b;
  } else if (b < 17408) {
    src = Wq; dst = wqkvb; off = b - 16384;
  } else if (b < 18432) {
    src = Wk; dst = wqkvb + 1048576; off = b - 17408;
  } else if (b < 19456) {
    src = Wv; dst = wqkvb + 2097152; off = b - 18432;
  } else {
    src = Wo; dst = wob; off = b - 19456;
  }
  const int i = (off * 256 + threadIdx.x) * 4;
  float4 f = *(const float4*)(src + i);
  ushort4 o;
  o.x = f2bf(f.x); o.y = f2bf(f.y); o.z = f2bf(f.z); o.w = f2bf(f.w);
  *(ushort4*)(dst + i) = o;
}

// ---------------- restructured bf16 GEMM: C = A @ BT^T -----------------------
// A staged via DOUBLE-BUFFERED global_load_lds (stage k+1 issued right after
// the barrier for k -> one iteration of slack before the drain; 1 barrier/iter).
// B fragments load straight from global (L2-resident weights) as VGPR loads,
// software-pipelined one iteration ahead -> never sit behind a vmcnt(0) drain
// with zero slack. XOR swizzle on A staging/fragments kills bank conflicts.
// MODE 0: N=3072 (q|k|v), bias b0/b1/b2, ReLU on q,k; bf16 out via
//         LDS-transposed 16B stores (2-wave rounds).
// MODE 1: N=1024, bias b0, f32 out via LDS-transposed 16B stores.
template <int MODE>
__global__ __launch_bounds__(256) void gemm_bt(
    const unsigned short* __restrict__ A,
    const unsigned short* __restrict__ BT,
    const float* __restrict__ b0, const float* __restrict__ b1,
    const float* __restrict__ b2,
    unsigned short* __restrict__ Oq, unsigned short* __restrict__ Ok,
    unsigned short* __restrict__ Ov, float* __restrict__ Of) {
  // MODE 0: max(dbuf lA 16384 B, epi 2x4608 shorts = 18432 B) = 9216 shorts.
  // MODE 1: max(16384 B, epi 2x(64x68 f32) = 34816 B) = 17408 shorts.
  __shared__ __align__(16) unsigned short smem[(MODE == 0) ? 9216 : 17408];
  unsigned short* lA = smem;  // two 4096-short buffers
  const int K = 1024;
  const int t = threadIdx.x;
  const int m0 = blockIdx.x * 128;
  const int n0 = blockIdx.y * 128;
  const int lane = t & 63;
  const int wv = t >> 6;
  const int wm = (wv & 1) * 64;
  const int wn = (wv >> 1) * 64;
  const int mrow = lane & 15;
  const int quad = lane >> 4;
  const int slot = quad ^ ((mrow >> 1) & 3);  // swizzled fragment slot

  const int srow = t >> 2;
  const int scol = (((t & 3) ^ ((srow >> 1) & 3))) * 8;  // swizzled stage chunk
  const unsigned short* gA0 = A + (size_t)(m0 + srow) * K + scol;
  const unsigned short* gA1 = A + (size_t)(m0 + 64 + srow) * K + scol;

  // B fragment base pointers (per j-tile); lane reads 16B at (row, kk+quad*8)
  const unsigned short* gB[4];
#pragma unroll
  for (int j = 0; j < 4; ++j)
    gB[j] = BT + (size_t)(n0 + wn + j * 16 + mrow) * K + quad * 8;

  floatx4 acc[4][4] = {};
  shortx8 bA[4], bB[4];

  // prologue: stage A tile 0 into buf0, load B frags for kk=0
  gload16(gA0, lA + t * 8);
  gload16(gA1, lA + 2048 + t * 8);
#pragma unroll
  for (int j = 0; j < 4; ++j) bA[j] = *(const shortx8*)(gB[j]);

  for (int kk = 0; kk < K; kk += 64) {
    // ---- half 1: consume buf0 + bA, prefetch buf1 + bB (kk+32, always valid)
    __syncthreads();
    gload16(gA0 + kk + 32, lA + 4096 + t * 8);
    gload16(gA1 + kk + 32, lA + 4096 + 2048 + t * 8);
    {
      shortx8 af[4];
#pragma unroll
      for (int i = 0; i < 4; ++i)
        af[i] = *(const shortx8*)&lA[(wm + i * 16 + mrow) * 32 + slot * 8];
#pragma unroll
      for (int j = 0; j < 4; ++j) bB[j] = *(const shortx8*)(gB[j] + kk + 32);
#pragma unroll
      for (int i = 0; i < 4; ++i)
#pragma unroll
        for (int j = 0; j < 4; ++j)
          acc[i][j] = __builtin_amdgcn_mfma_f32_16x16x32_bf16(af[i], bA[j],
                                                              acc[i][j], 0, 0, 0);
    }
    // ---- half 2: consume buf1 + bB, prefetch buf0 + bA (kk+64, guarded)
    __syncthreads();
    const bool pf = (kk + 64) < K;
    if (pf) {
      gload16(gA0 + kk + 64, lA + t * 8);
      gload16(gA1 + kk + 64, lA + 2048 + t * 8);
    }
    {
      shortx8 af[4];
#pragma unroll
      for (int i = 0; i < 4; ++i)
        af[i] = *(const shortx8*)&lA[4096 + (wm + i * 16 + mrow) * 32 + slot * 8];
      if (pf) {
#pragma unroll
        for (int j = 0; j < 4; ++j) bA[j] = *(const shortx8*)(gB[j] + kk + 64);
      }
#pragma unroll
      for (int i = 0; i < 4; ++i)
#pragma unroll
        for (int j = 0; j < 4; ++j)
          acc[i][j] = __builtin_amdgcn_mfma_f32_16x16x32_bf16(af[i], bB[j],
                                                              acc[i][j], 0, 0, 0);
    }
  }
  __syncthreads();  // smem reuse below

  if (MODE == 0) {
    const int sel = n0 >> 10;
    const float* bb = (sel == 0) ? b0 : ((sel == 1) ? b1 : b2);
    unsigned short* O = (sel == 0) ? Oq : ((sel == 1) ? Ok : Ov);
    const int nb2 = (n0 & 1023) + wn;
    unsigned short* we = smem + (wv & 1) * 4608;  // 64x72 bf16 per wave
    const int r8 = lane >> 3;
    const int c8 = lane & 7;
#pragma unroll
    for (int round = 0; round < 2; ++round) {
      if ((wv >> 1) == round) {
#pragma unroll
        for (int j = 0; j < 4; ++j) {
          const int coll = j * 16 + mrow;
          const float bias = bb[nb2 + coll];
#pragma unroll
          for (int i = 0; i < 4; ++i) {
#pragma unroll
            for (int r = 0; r < 4; ++r) {
              float v = acc[i][j][r] + bias;
              if (sel < 2) v = fmaxf(v, 0.0f);
              we[(i * 16 + quad * 4 + r) * 72 + coll] = f2bf(v);
            }
          }
        }
      }
      __syncthreads();
      if ((wv >> 1) == round) {
#pragma unroll
        for (int p = 0; p < 8; ++p) {
          const int rowl = r8 + p * 8;
          uint4 v = *(const uint4*)&we[rowl * 72 + c8 * 8];
          *(uint4*)&O[(size_t)(m0 + wm + rowl) * 1024 + nb2 + c8 * 8] = v;
        }
      }
      __syncthreads();
    }
  } else {
    float* we = (float*)smem + (wv & 1) * (64 * 68);  // 64x68 f32 per wave
    const int r8 = lane >> 3;
    const int c8 = lane & 7;
#pragma unroll
    for (int round = 0; round < 2; ++round) {
      if ((wv >> 1) == round) {
#pragma unroll
        for (int j = 0; j < 4; ++j) {
          const int coll = j * 16 + mrow;
          const float bias = b0[n0 + wn + coll];
#pragma unroll
          for (int i = 0; i < 4; ++i) {
#pragma unroll
            for (int r = 0; r < 4; ++r)
              we[(i * 16 + quad * 4 + r) * 68 + coll] = acc[i][j][r] + bias;
          }
        }
      }
      __syncthreads();
      if ((wv >> 1) == round) {
#pragma unroll
        for (int p = 0; p < 8; ++p) {
          const int rowl = r8 + p * 8;
          float4 v0 = *(const float4*)&we[rowl * 68 + c8 * 8];
          float4 v1 = *(const float4*)&we[rowl * 68 + c8 * 8 + 4];
          float* dst = Of + (size_t)(m0 + wm + rowl) * 1024 + n0 + wn + c8 * 8;
          *(float4*)dst = v0;
          *(float4*)(dst + 4) = v1;
        }
      }
      __syncthreads();
    }
  }
}

// ---------------- fused retention (one axis): out = S @ (K^T V) per (outer, head)
__global__ __launch_bounds__(256) void retention_fused(
    const unsigned short* __restrict__ S, const unsigned short* __restrict__ Kb,
    const unsigned short* __restrict__ Vb, unsigned short* __restrict__ D,
    int axis) {
  const int outer = blockIdx.x;
  const int n = blockIdx.y;
  __shared__ unsigned short lS[128 * 72];
  __shared__ unsigned short lKT[64 * 136];
  __shared__ unsigned short lVT[64 * 136];
  unsigned short* lKV = lVT;  // reused for kv^T [e][d] stride 72 after stage 1
  const int t = threadIdx.x;
  const size_t base = (axis == 0) ? ((size_t)outer << 17) : ((size_t)outer << 10);
  const size_t istr = (axis == 0) ? (size_t)1024 : (size_t)131072;
  const size_t nof = (size_t)(n << 6);

#pragma unroll
  for (int it = 0; it < 4; ++it) {
    const int r = it * 32 + (t >> 3);
    const int c = (t & 7) * 8;
    uint4 v = *(const uint4*)&S[base + (size_t)r * istr + nof + c];
    *(uint4*)&lS[r * 72 + c] = v;
  }
#pragma unroll
  for (int it = 0; it < 4; ++it) {
    const int w = it * 32 + (t & 31);
    const int d0 = (t >> 5) * 8;
    const size_t g = base + (size_t)w * istr + nof + d0;
    uint4 k4 = *(const uint4*)&Kb[g];
    uint4 v4 = *(const uint4*)&Vb[g];
    const unsigned short* kp = (const unsigned short*)&k4;
    const unsigned short* vp = (const unsigned short*)&v4;
#pragma unroll
    for (int i = 0; i < 8; ++i) {
      lKT[(d0 + i) * 136 + w] = kp[i];
      lVT[(d0 + i) * 136 + w] = vp[i];
    }
  }
  __syncthreads();

  const int lane = t & 63;
  const int wv = t >> 6;
  const int mrow = lane & 15;
  const int quad = lane >> 4;

  floatx4 acc1[4] = {};
#pragma unroll
  for (int ks = 0; ks < 4; ++ks) {
    shortx8 a = *(const shortx8*)&lVT[(wv * 16 + mrow) * 136 + ks * 32 + quad * 8];
#pragma unroll
    for (int j = 0; j < 4; ++j) {
      shortx8 b = *(const shortx8*)&lKT[(j * 16 + mrow) * 136 + ks * 32 + quad * 8];
      acc1[j] = __builtin_amdgcn_mfma_f32_16x16x32_bf16(a, b, acc1[j], 0, 0, 0);
    }
  }
  __syncthreads();  // all stage-1 reads of lVT done before aliasing as lKV
#pragma unroll
  for (int j = 0; j < 4; ++j)
#pragma unroll
    for (int r = 0; r < 4; ++r)
      lKV[(wv * 16 + quad * 4 + r) * 72 + j * 16 + mrow] = f2bf(acc1[j][r]);
  __syncthreads();

  floatx4 acc2[2][4] = {};
#pragma unroll
  for (int ks = 0; ks < 2; ++ks) {
    shortx8 a2[2], b2[4];
#pragma unroll
    for (int i = 0; i < 2; ++i)
      a2[i] = *(const shortx8*)&lS[(wv * 32 + i * 16 + mrow) * 72 + ks * 32 + quad * 8];
#pragma unroll
    for (int j = 0; j < 4; ++j)
      b2[j] = *(const shortx8*)&lKV[(j * 16 + mrow) * 72 + ks * 32 + quad * 8];
#pragma unroll
    for (int i = 0; i < 2; ++i)
#pragma unroll
      for (int j = 0; j < 4; ++j)
        acc2[i][j] = __builtin_amdgcn_mfma_f32_16x16x32_bf16(a2[i], b2[j],
                                                             acc2[i][j], 0, 0, 0);
  }
#pragma unroll
  for (int i = 0; i < 2; ++i)
#pragma unroll
    for (int j = 0; j < 4; ++j)
#pragma unroll
      for (int r = 0; r < 4; ++r) {
        const int row = wv * 32 + i * 16 + quad * 4 + r;
        const int col = j * 16 + mrow;
        D[base + (size_t)row * istr + nof + col] = f2bf(acc2[i][j][r]);
      }
}

extern "C" void kernel_launch(void* const* d_in, const int* in_sizes, int n_in,
                              void* d_out, int out_size, void* d_ws, size_t ws_size,
                              hipStream_t stream) {
  const float* x  = (const float*)d_in[0];
  const float* Wq = (const float*)d_in[1];
  const float* bq = (const float*)d_in[2];
  const float* Wk = (const float*)d_in[3];
  const float* bk = (const float*)d_in[4];
  const float* Wv = (const float*)d_in[5];
  const float* bv = (const float*)d_in[6];
  const float* Wo = (const float*)d_in[7];
  const float* bo = (const float*)d_in[8];
  float* out = (float*)d_out;

  char* ws = (char*)d_ws;
  unsigned short* xb    = (unsigned short*)(ws + 0);          // 16M elem
  unsigned short* wqkvb = (unsigned short*)(ws + 33554432);   // 3M elem
  unsigned short* wob   = (unsigned short*)(ws + 39845888);   // 1M elem
  unsigned short* qb    = (unsigned short*)(ws + 41943040);   // 16M elem
  unsigned short* kb    = (unsigned short*)(ws + 75497472);   // 16M elem
  unsigned short* vb    = (unsigned short*)(ws + 109051904);  // 16M elem
  unsigned short* out1  = xb;  // reuse: x not needed after projections
  unsigned short* out2  = qb;  // reuse: q not needed after axis-0 retention

  cvt_all<<<dim3(20480), dim3(256), 0, stream>>>(x, Wq, Wk, Wv, Wo, xb, wqkvb, wob);
  gemm_bt<0><<<dim3(128, 24), dim3(256), 0, stream>>>(
      xb, wqkvb, bq, bk, bv, qb, kb, vb, (float*)nullptr);
  retention_fused<<<dim3(128, 16), dim3(256), 0, stream>>>(qb, kb, vb, out1, 0);
  retention_fused<<<dim3(128, 16), dim3(256), 0, stream>>>(out1, kb, vb, out2, 1);
  gemm_bt<1><<<dim3(128, 8), dim3(256), 0, stream>>>(
      out2, wob, bo, nullptr, nullptr, nullptr, nullptr, nullptr, out);
}

// Round 5
// 353.495 us; speedup vs baseline: 1.3753x; 1.3753x over previous
//
#include <hip/hip_runtime.h>
#include <hip/hip_bf16.h>
#include <stdint.h>

// Problem dims (fixed): x [1,128,128,1024], E=1024, NH=16, D=64, M=16384.

typedef __attribute__((ext_vector_type(4))) float floatx4;
typedef __attribute__((ext_vector_type(8))) short shortx8;

static __device__ __forceinline__ float bf2f(unsigned short h) {
  return __uint_as_float(((unsigned int)h) << 16);
}
static __device__ __forceinline__ unsigned short f2bf(float f) {
  unsigned int u = __float_as_uint(f);
  u += 0x7fffu + ((u >> 16) & 1u);  // RNE
  return (unsigned short)(u >> 16);
}

static __device__ __forceinline__ void gload16(const void* g, void* l) {
  __builtin_amdgcn_global_load_lds(
      (const __attribute__((address_space(1))) void*)g,
      (__attribute__((address_space(3))) void*)l, 16, 0, 0);
}

// ---------------- merged f32 -> bf16 convert ----------------
__global__ __launch_bounds__(256) void cvt_all(
    const float* __restrict__ x, const float* __restrict__ Wq,
    const float* __restrict__ Wk, const float* __restrict__ Wv,
    const float* __restrict__ Wo, unsigned short* __restrict__ xb,
    unsigned short* __restrict__ wqkvb, unsigned short* __restrict__ wob) {
  const int b = blockIdx.x;
  const float* src;
  unsigned short* dst;
  int off;
  if (b < 16384) {
    src = x; dst = xb; off = b;
  } else if (b < 17408) {
    src = Wq; dst = wqkvb; off = b - 16384;
  } else if (b < 18432) {
    src = Wk; dst = wqkvb + 1048576; off = b - 17408;
  } else if (b < 19456) {
    src = Wv; dst = wqkvb + 2097152; off = b - 18432;
  } else {
    src = Wo; dst = wob; off = b - 19456;
  }
  const int i = (off * 256 + threadIdx.x) * 4;
  float4 f = *(const float4*)(src + i);
  ushort4 o;
  o.x = f2bf(f.x); o.y = f2bf(f.y); o.z = f2bf(f.z); o.w = f2bf(f.w);
  *(ushort4*)(dst + i) = o;
}

// ---------------- m97-style bf16 GEMM with XOR-swizzled LDS: C = A @ BT^T ----
// (R3 K-loop restored verbatim — source-level pipelining against the barrier
// drain regressed in R4; the 2-barrier structure is the working plateau.)
// MODE 0: N=3072 (q|k|v), bias b0/b1/b2, ReLU on q,k; bf16 out, LDS-transposed
//         16B stores. MODE 1: N=1024, bias b0, f32 out, LDS-transposed stores.
template <int MODE>
__global__ __launch_bounds__(256) void gemm_bt(
    const unsigned short* __restrict__ A,
    const unsigned short* __restrict__ BT,
    const float* __restrict__ b0, const float* __restrict__ b1,
    const float* __restrict__ b2,
    unsigned short* __restrict__ Oq, unsigned short* __restrict__ Ok,
    unsigned short* __restrict__ Ov, float* __restrict__ Of) {
  // 36,864 B shared: K-loop uses first 16 KiB (lA|lB); epilogue reuses it.
  __shared__ __align__(16) unsigned short smem[18432];
  unsigned short* lA = smem;         // 128*32
  unsigned short* lB = smem + 4096;  // 128*32
  const int K = 1024;
  const int t = threadIdx.x;
  const int m0 = blockIdx.x * 128;
  const int n0 = blockIdx.y * 128;
  const int lane = t & 63;
  const int wv = t >> 6;
  const int wm = (wv & 1) * 64;
  const int wn = (wv >> 1) * 64;
  const int mrow = lane & 15;
  const int quad = lane >> 4;
  const int slot = quad ^ ((mrow >> 1) & 3);  // swizzled fragment slot

  const int srow = t >> 2;
  const int scol = (((t & 3) ^ ((srow >> 1) & 3))) * 8;  // swizzled stage chunk
  const unsigned short* gA0 = A + (size_t)(m0 + srow) * K + scol;
  const unsigned short* gA1 = A + (size_t)(m0 + 64 + srow) * K + scol;
  const unsigned short* gB0 = BT + (size_t)(n0 + srow) * K + scol;
  const unsigned short* gB1 = BT + (size_t)(n0 + 64 + srow) * K + scol;
  unsigned short* lA0 = &lA[t * 8];
  unsigned short* lA1 = &lA[2048 + t * 8];
  unsigned short* lB0 = &lB[t * 8];
  unsigned short* lB1 = &lB[2048 + t * 8];

  floatx4 acc[4][4] = {};
  for (int kk = 0; kk < K; kk += 32) {
    gload16(gA0 + kk, lA0);
    gload16(gA1 + kk, lA1);
    gload16(gB0 + kk, lB0);
    gload16(gB1 + kk, lB1);
    __syncthreads();
    shortx8 af[4], bfr[4];
#pragma unroll
    for (int i = 0; i < 4; ++i)
      af[i] = *(const shortx8*)&lA[(wm + i * 16 + mrow) * 32 + slot * 8];
#pragma unroll
    for (int j = 0; j < 4; ++j)
      bfr[j] = *(const shortx8*)&lB[(wn + j * 16 + mrow) * 32 + slot * 8];
#pragma unroll
    for (int i = 0; i < 4; ++i)
#pragma unroll
      for (int j = 0; j < 4; ++j)
        acc[i][j] = __builtin_amdgcn_mfma_f32_16x16x32_bf16(af[i], bfr[j],
                                                            acc[i][j], 0, 0, 0);
    __syncthreads();
  }

  if (MODE == 0) {
    const int sel = n0 >> 10;
    const float* bb = (sel == 0) ? b0 : ((sel == 1) ? b1 : b2);
    unsigned short* O = (sel == 0) ? Oq : ((sel == 1) ? Ok : Ov);
    const int nb = n0 & 1023;
    unsigned short* we = smem + wv * 4608;  // 64x72 bf16 per wave
#pragma unroll
    for (int j = 0; j < 4; ++j) {
      const int coll = j * 16 + mrow;
      const float bias = bb[nb + wn + coll];
#pragma unroll
      for (int i = 0; i < 4; ++i) {
#pragma unroll
        for (int r = 0; r < 4; ++r) {
          const int rowl = i * 16 + quad * 4 + r;
          float v = acc[i][j][r] + bias;
          if (sel < 2) v = fmaxf(v, 0.0f);
          we[rowl * 72 + coll] = f2bf(v);
        }
      }
    }
    __syncthreads();
    const int r8 = lane >> 3;
    const int c8 = lane & 7;
#pragma unroll
    for (int p = 0; p < 8; ++p) {
      const int rowl = r8 + p * 8;
      uint4 v = *(const uint4*)&we[rowl * 72 + c8 * 8];
      *(uint4*)&O[(size_t)(m0 + wm + rowl) * 1024 + nb + wn + c8 * 8] = v;
    }
  } else {
    // f32 out via 2-round LDS transpose (2 x 64x68 f32 tiles = 34,816 B)
    float* wef = (float*)smem;
    float* we = wef + (wv & 1) * (64 * 68);
    const int r8 = lane >> 3;
    const int c8 = lane & 7;
#pragma unroll
    for (int round = 0; round < 2; ++round) {
      if ((wv >> 1) == round) {
#pragma unroll
        for (int j = 0; j < 4; ++j) {
          const int coll = j * 16 + mrow;
          const float bias = b0[n0 + wn + coll];
#pragma unroll
          for (int i = 0; i < 4; ++i) {
#pragma unroll
            for (int r = 0; r < 4; ++r)
              we[(i * 16 + quad * 4 + r) * 68 + coll] = acc[i][j][r] + bias;
          }
        }
      }
      __syncthreads();
      if ((wv >> 1) == round) {
#pragma unroll
        for (int p = 0; p < 8; ++p) {
          const int rowl = r8 + p * 8;
          float4 v0 = *(const float4*)&we[rowl * 68 + c8 * 8];
          float4 v1 = *(const float4*)&we[rowl * 68 + c8 * 8 + 4];
          float* dst = Of + (size_t)(m0 + wm + rowl) * 1024 + n0 + wn + c8 * 8;
          *(float4*)dst = v0;
          *(float4*)(dst + 4) = v1;
        }
      }
      __syncthreads();
    }
  }
}

// ---------------- fused retention (one axis): out = S @ (K^T V) per (outer, head)
__global__ __launch_bounds__(256) void retention_fused(
    const unsigned short* __restrict__ S, const unsigned short* __restrict__ Kb,
    const unsigned short* __restrict__ Vb, unsigned short* __restrict__ D,
    int axis) {
  const int outer = blockIdx.x;
  const int n = blockIdx.y;
  __shared__ unsigned short lS[128 * 72];
  __shared__ unsigned short lKT[64 * 136];
  __shared__ unsigned short lVT[64 * 136];
  unsigned short* lKV = lVT;  // reused for kv^T [e][d] stride 72 after stage 1
  const int t = threadIdx.x;
  const size_t base = (axis == 0) ? ((size_t)outer << 17) : ((size_t)outer << 10);
  const size_t istr = (axis == 0) ? (size_t)1024 : (size_t)131072;
  const size_t nof = (size_t)(n << 6);

#pragma unroll
  for (int it = 0; it < 4; ++it) {
    const int r = it * 32 + (t >> 3);
    const int c = (t & 7) * 8;
    uint4 v = *(const uint4*)&S[base + (size_t)r * istr + nof + c];
    *(uint4*)&lS[r * 72 + c] = v;
  }
#pragma unroll
  for (int it = 0; it < 4; ++it) {
    const int w = it * 32 + (t & 31);
    const int d0 = (t >> 5) * 8;
    const size_t g = base + (size_t)w * istr + nof + d0;
    uint4 k4 = *(const uint4*)&Kb[g];
    uint4 v4 = *(const uint4*)&Vb[g];
    const unsigned short* kp = (const unsigned short*)&k4;
    const unsigned short* vp = (const unsigned short*)&v4;
#pragma unroll
    for (int i = 0; i < 8; ++i) {
      lKT[(d0 + i) * 136 + w] = kp[i];
      lVT[(d0 + i) * 136 + w] = vp[i];
    }
  }
  __syncthreads();

  const int lane = t & 63;
  const int wv = t >> 6;
  const int mrow = lane & 15;
  const int quad = lane >> 4;

  floatx4 acc1[4] = {};
#pragma unroll
  for (int ks = 0; ks < 4; ++ks) {
    shortx8 a = *(const shortx8*)&lVT[(wv * 16 + mrow) * 136 + ks * 32 + quad * 8];
#pragma unroll
    for (int j = 0; j < 4; ++j) {
      shortx8 b = *(const shortx8*)&lKT[(j * 16 + mrow) * 136 + ks * 32 + quad * 8];
      acc1[j] = __builtin_amdgcn_mfma_f32_16x16x32_bf16(a, b, acc1[j], 0, 0, 0);
    }
  }
  __syncthreads();  // all stage-1 reads of lVT done before aliasing as lKV
#pragma unroll
  for (int j = 0; j < 4; ++j)
#pragma unroll
    for (int r = 0; r < 4; ++r)
      lKV[(wv * 16 + quad * 4 + r) * 72 + j * 16 + mrow] = f2bf(acc1[j][r]);
  __syncthreads();

  floatx4 acc2[2][4] = {};
#pragma unroll
  for (int ks = 0; ks < 2; ++ks) {
    shortx8 a2[2], b2[4];
#pragma unroll
    for (int i = 0; i < 2; ++i)
      a2[i] = *(const shortx8*)&lS[(wv * 32 + i * 16 + mrow) * 72 + ks * 32 + quad * 8];
#pragma unroll
    for (int j = 0; j < 4; ++j)
      b2[j] = *(const shortx8*)&lKV[(j * 16 + mrow) * 72 + ks * 32 + quad * 8];
#pragma unroll
    for (int i = 0; i < 2; ++i)
#pragma unroll
      for (int j = 0; j < 4; ++j)
        acc2[i][j] = __builtin_amdgcn_mfma_f32_16x16x32_bf16(a2[i], b2[j],
                                                             acc2[i][j], 0, 0, 0);
  }
  // Epilogue: round-trip C through lS (128x72) -> 16B/lane coalesced stores
  // (was: 64 scalar 2B stores/thread -> 32B HBM segments).
  __syncthreads();  // all stage-2 reads of lS done
#pragma unroll
  for (int i = 0; i < 2; ++i)
#pragma unroll
    for (int j = 0; j < 4; ++j)
#pragma unroll
      for (int r = 0; r < 4; ++r) {
        const int row = wv * 32 + i * 16 + quad * 4 + r;
        const int col = j * 16 + mrow;
        lS[row * 72 + col] = f2bf(acc2[i][j][r]);
      }
  __syncthreads();
#pragma unroll
  for (int it = 0; it < 4; ++it) {
    const int row = it * 32 + (t >> 3);
    const int c = (t & 7) * 8;
    uint4 v = *(const uint4*)&lS[row * 72 + c];
    *(uint4*)&D[base + (size_t)row * istr + nof + c] = v;
  }
}

extern "C" void kernel_launch(void* const* d_in, const int* in_sizes, int n_in,
                              void* d_out, int out_size, void* d_ws, size_t ws_size,
                              hipStream_t stream) {
  const float* x  = (const float*)d_in[0];
  const float* Wq = (const float*)d_in[1];
  const float* bq = (const float*)d_in[2];
  const float* Wk = (const float*)d_in[3];
  const float* bk = (const float*)d_in[4];
  const float* Wv = (const float*)d_in[5];
  const float* bv = (const float*)d_in[6];
  const float* Wo = (const float*)d_in[7];
  const float* bo = (const float*)d_in[8];
  float* out = (float*)d_out;

  char* ws = (char*)d_ws;
  unsigned short* xb    = (unsigned short*)(ws + 0);          // 16M elem
  unsigned short* wqkvb = (unsigned short*)(ws + 33554432);   // 3M elem
  unsigned short* wob   = (unsigned short*)(ws + 39845888);   // 1M elem
  unsigned short* qb    = (unsigned short*)(ws + 41943040);   // 16M elem
  unsigned short* kb    = (unsigned short*)(ws + 75497472);   // 16M elem
  unsigned short* vb    = (unsigned short*)(ws + 109051904);  // 16M elem
  unsigned short* out1  = xb;  // reuse: x not needed after projections
  unsigned short* out2  = qb;  // reuse: q not needed after axis-0 retention

  cvt_all<<<dim3(20480), dim3(256), 0, stream>>>(x, Wq, Wk, Wv, Wo, xb, wqkvb, wob);
  gemm_bt<0><<<dim3(128, 24), dim3(256), 0, stream>>>(
      xb, wqkvb, bq, bk, bv, qb, kb, vb, (float*)nullptr);
  retention_fused<<<dim3(128, 16), dim3(256), 0, stream>>>(qb, kb, vb, out1, 0);
  retention_fused<<<dim3(128, 16), dim3(256), 0, stream>>>(out1, kb, vb, out2, 1);
  gemm_bt<1><<<dim3(128, 8), dim3(256), 0, stream>>>(
      out2, wob, bo, nullptr, nullptr, nullptr, nullptr, nullptr, out);
}